// Round 1
// baseline (4705.885 us; speedup 1.0000x reference)
//
#include <hip/hip_runtime.h>
#include <stdint.h>

#define H_DIM 4096
#define V_DIM 32000
#define B_DIM 8
#define T_DIM 512
#define M_PER (B_DIM * T_DIM)   // 4096 tokens per model
#define BETA 0.1f
#define IGNORE_IDX (-100)

#define BM 128
#define BN 128
#define BK 32
#define MTILES (M_PER / BM)     // 32
#define NTILES (V_DIM / BN)     // 250

typedef __attribute__((ext_vector_type(8))) short bf16x8;
typedef __attribute__((ext_vector_type(4))) float f32x4;

#define GAS(p) ((const __attribute__((address_space(1))) void*)(p))
#define LAS(p) ((__attribute__((address_space(3))) void*)(p))

// ---------------- fp32 -> bf16 (RNE) convert, float4-vectorized ----------------
__device__ __forceinline__ unsigned short f32_to_bf16(float f) {
    unsigned int u = __float_as_uint(f);
    u = (u + 0x7FFFu + ((u >> 16) & 1u)) >> 16;
    return (unsigned short)u;
}

__global__ void convert_kernel(const float* __restrict__ src,
                               unsigned short* __restrict__ dst, int n4) {
    int stride = gridDim.x * blockDim.x;
    const float4* s4 = (const float4*)src;
    ushort4* d4 = (ushort4*)dst;
    for (int i = blockIdx.x * blockDim.x + threadIdx.x; i < n4; i += stride) {
        float4 v = s4[i];
        ushort4 o;
        o.x = f32_to_bf16(v.x);
        o.y = f32_to_bf16(v.y);
        o.z = f32_to_bf16(v.z);
        o.w = f32_to_bf16(v.w);
        d4[i] = o;
    }
}

// ---------------- fused GEMM + per-tile softmax partials ----------------
// grid: x = MTILES*NTILES (mt = bx&31 fast so 32 blocks share a W-tile), y = model
__global__ __launch_bounds__(256)
void gemm_lse_kernel(const unsigned short* __restrict__ Xb,  // [2][M_PER][H] bf16
                     const unsigned short* __restrict__ Wb,  // [2][V][H] bf16
                     const long long* __restrict__ y,        // [M_PER]
                     float* __restrict__ pmax,               // [2][NTILES][M_PER]
                     float* __restrict__ psum,               // [2][NTILES][M_PER]
                     float* __restrict__ tgt)                // [2][M_PER]
{
    __shared__ alignas(16) unsigned short Alds[BM * BK];  // 8 KB
    __shared__ alignas(16) unsigned short Blds[BN * BK];  // 8 KB
    __shared__ float smax[BM][2];
    __shared__ float ssum[BM][2];
    __shared__ int ylds[BM];

    const int tid = threadIdx.x;
    const int bx = blockIdx.x;
    const int model = blockIdx.y;
    const int mt = bx & (MTILES - 1);
    const int nt = bx >> 5;
    const int m0 = mt * BM;
    const int n0 = nt * BN;

    const unsigned short* Abase = Xb + ((size_t)model * M_PER + m0) * H_DIM;
    const unsigned short* Bbase = Wb + ((size_t)model * V_DIM + n0) * H_DIM;

    if (tid < BM) ylds[tid] = (int)y[m0 + tid];

    const int wave = tid >> 6;
    const int lane = tid & 63;
    const int wm = wave >> 1;
    const int wn = wave & 1;
    const int l15 = lane & 15;
    const int quad = lane >> 4;

    f32x4 acc[4][4];
#pragma unroll
    for (int i = 0; i < 4; ++i)
#pragma unroll
        for (int j = 0; j < 4; ++j) acc[i][j] = {0.f, 0.f, 0.f, 0.f};

    // staging: 128x32 bf16 tile = 8KB = 256 threads x 2 chunks x 16B
    const int c0 = tid, c1 = 256 + tid;
    const int r0 = c0 >> 2, kc0 = (c0 & 3) * 8;
    const int r1 = c1 >> 2, kc1 = (c1 & 3) * 8;
    const unsigned short* ga0 = Abase + (size_t)r0 * H_DIM + kc0;
    const unsigned short* ga1 = Abase + (size_t)r1 * H_DIM + kc1;
    const unsigned short* gb0 = Bbase + (size_t)r0 * H_DIM + kc0;
    const unsigned short* gb1 = Bbase + (size_t)r1 * H_DIM + kc1;

    for (int k0 = 0; k0 < H_DIM; k0 += BK) {
        __builtin_amdgcn_global_load_lds(GAS(ga0 + k0), LAS(Alds + c0 * 8), 16, 0, 0);
        __builtin_amdgcn_global_load_lds(GAS(ga1 + k0), LAS(Alds + c1 * 8), 16, 0, 0);
        __builtin_amdgcn_global_load_lds(GAS(gb0 + k0), LAS(Blds + c0 * 8), 16, 0, 0);
        __builtin_amdgcn_global_load_lds(GAS(gb1 + k0), LAS(Blds + c1 * 8), 16, 0, 0);
        __syncthreads();

        bf16x8 af[4], bfr[4];
#pragma unroll
        for (int i = 0; i < 4; ++i) {
            af[i]  = *(const bf16x8*)&Alds[(64 * wm + 16 * i + l15) * BK + quad * 8];
            bfr[i] = *(const bf16x8*)&Blds[(64 * wn + 16 * i + l15) * BK + quad * 8];
        }
#pragma unroll
        for (int i = 0; i < 4; ++i)
#pragma unroll
            for (int j = 0; j < 4; ++j)
                acc[i][j] = __builtin_amdgcn_mfma_f32_16x16x32_bf16(af[i], bfr[j], acc[i][j], 0, 0, 0);
        __syncthreads();
    }

    // epilogue: per-row (of 128) max + sumexp over this 128-col tile; capture target logit
    const size_t m_abs_base = (size_t)model * M_PER + m0;
#pragma unroll
    for (int i = 0; i < 4; ++i) {
#pragma unroll
        for (int r = 0; r < 4; ++r) {
            int row_local = 64 * wm + 16 * i + 4 * quad + r;
            float v0 = acc[i][0][r], v1 = acc[i][1][r], v2 = acc[i][2][r], v3 = acc[i][3][r];
            float mx = fmaxf(fmaxf(v0, v1), fmaxf(v2, v3));
#pragma unroll
            for (int s = 1; s < 16; s <<= 1) mx = fmaxf(mx, __shfl_xor(mx, s));
            float se = __expf(v0 - mx) + __expf(v1 - mx) + __expf(v2 - mx) + __expf(v3 - mx);
#pragma unroll
            for (int s = 1; s < 16; s <<= 1) se += __shfl_xor(se, s);
            if (l15 == 0) { smax[row_local][wn] = mx; ssum[row_local][wn] = se; }
            int yt = ylds[row_local] - n0;
            if (yt >= 0 && yt < BN) {
                int wny = yt >> 6, rem = yt & 63, jy = rem >> 4, ly = rem & 15;
                if (wny == wn && ly == l15) {
                    float tv = (jy == 0) ? v0 : ((jy == 1) ? v1 : ((jy == 2) ? v2 : v3));
                    tgt[m_abs_base + row_local] = tv;
                }
            }
        }
    }
    __syncthreads();
    if (tid < BM) {
        float ma = smax[tid][0], mb = smax[tid][1];
        float M = fmaxf(ma, mb);
        float S = ssum[tid][0] * __expf(ma - M) + ssum[tid][1] * __expf(mb - M);
        size_t off = ((size_t)model * NTILES + nt) * M_PER + m0 + tid;
        pmax[off] = M;
        psum[off] = S;
    }
}

// ---------------- combine partials -> per-sequence (sum logp, count) ----------------
__global__ void combine_kernel(const float* __restrict__ pmax, const float* __restrict__ psum,
                               const float* __restrict__ tgt, const long long* __restrict__ y,
                               float* __restrict__ seqstat /* [2][B][2] */) {
    int b = blockIdx.x;
    int model = blockIdx.y;
    int tid = threadIdx.x;
    float lp = 0.f, cnt = 0.f;
    for (int tt = tid; tt < T_DIM; tt += blockDim.x) {
        int m = b * T_DIM + tt;
        long long yv = y[m];
        if (yv == IGNORE_IDX) continue;
        float gm = -3.4e38f, gs = 0.f;
        for (int nt = 0; nt < NTILES; ++nt) {
            size_t off = ((size_t)model * NTILES + nt) * M_PER + m;
            float pm = pmax[off], ps = psum[off];
            if (pm > gm) { gs = gs * __expf(gm - pm) + ps; gm = pm; }
            else         { gs += ps * __expf(pm - gm); }
        }
        float lse = gm + __logf(gs);
        lp += tgt[(size_t)model * M_PER + m] - lse;
        cnt += 1.f;
    }
#pragma unroll
    for (int s = 32; s; s >>= 1) { lp += __shfl_down(lp, s); cnt += __shfl_down(cnt, s); }
    __shared__ float red[4][2];
    int w = tid >> 6;
    if ((tid & 63) == 0) { red[w][0] = lp; red[w][1] = cnt; }
    __syncthreads();
    if (tid == 0) {
        float sl = 0.f, sc = 0.f;
        for (int i = 0; i < 4; ++i) { sl += red[i][0]; sc += red[i][1]; }
        seqstat[(model * B_DIM + b) * 2 + 0] = sl;
        seqstat[(model * B_DIM + b) * 2 + 1] = sc;
    }
}

// ---------------- final DPO loss ----------------
__global__ void loss_kernel(const float* __restrict__ seqstat, float* __restrict__ out) {
    if (threadIdx.x == 0 && blockIdx.x == 0) {
        float loss = 0.f;
        for (int i = 0; i < B_DIM / 2; ++i) {
            float polc = seqstat[(0 * B_DIM + i) * 2] / fmaxf(seqstat[(0 * B_DIM + i) * 2 + 1], 1.f);
            float refc = seqstat[(1 * B_DIM + i) * 2] / fmaxf(seqstat[(1 * B_DIM + i) * 2 + 1], 1.f);
            float polr = seqstat[(0 * B_DIM + i + 4) * 2] / fmaxf(seqstat[(0 * B_DIM + i + 4) * 2 + 1], 1.f);
            float refr = seqstat[(1 * B_DIM + i + 4) * 2] / fmaxf(seqstat[(1 * B_DIM + i + 4) * 2 + 1], 1.f);
            float d = BETA * ((polc - refc) - (polr - refr));
            float ls = fminf(d, 0.f) - log1pf(__expf(-fabsf(d)));  // log_sigmoid(d), stable
            loss -= ls;
        }
        out[0] = loss / (float)(B_DIM / 2);
    }
}

extern "C" void kernel_launch(void* const* d_in, const int* in_sizes, int n_in,
                              void* d_out, int out_size, void* d_ws, size_t ws_size,
                              hipStream_t stream) {
    const float* x      = (const float*)d_in[0];
    const float* ref_x  = (const float*)d_in[1];
    const long long* y  = (const long long*)d_in[2];
    const float* W      = (const float*)d_in[3];
    const float* ref_W  = (const float*)d_in[4];
    float* out = (float*)d_out;

    // workspace layout (bytes): Xb[2*M*H]*2  Wb[2*V*H]*2  pmax  psum  tgt  seqstat
    char* ws = (char*)d_ws;
    unsigned short* Xb = (unsigned short*)ws;
    unsigned short* Wb = (unsigned short*)(ws + (size_t)2 * M_PER * H_DIM * 2);
    float* pmax = (float*)(ws + (size_t)2 * M_PER * H_DIM * 2 + (size_t)2 * V_DIM * H_DIM * 2);
    float* psum = pmax + (size_t)2 * NTILES * M_PER;
    float* tgt  = psum + (size_t)2 * NTILES * M_PER;
    float* seqstat = tgt + (size_t)2 * M_PER;

    const int nx4 = M_PER * H_DIM / 4;   // 4,194,304
    const int nw4 = V_DIM * H_DIM / 4;   // 32,768,000
    convert_kernel<<<4096, 256, 0, stream>>>(x, Xb, nx4);
    convert_kernel<<<4096, 256, 0, stream>>>(ref_x, Xb + (size_t)M_PER * H_DIM, nx4);
    convert_kernel<<<16384, 256, 0, stream>>>(W, Wb, nw4);
    convert_kernel<<<16384, 256, 0, stream>>>(ref_W, Wb + (size_t)V_DIM * H_DIM, nw4);

    dim3 grid(MTILES * NTILES, 2);
    gemm_lse_kernel<<<grid, 256, 0, stream>>>(Xb, Wb, y, pmax, psum, tgt);

    combine_kernel<<<dim3(B_DIM, 2), 256, 0, stream>>>(pmax, psum, tgt, y, seqstat);
    loss_kernel<<<1, 64, 0, stream>>>(seqstat, out);
}